// Round 9
// baseline (210.048 us; speedup 1.0000x reference)
//
#include <hip/hip_runtime.h>

#define NN    50000
#define NE    800000
#define INF_  256
#define HIDF  128
#define OUTF  64
#define NBUCK 196        // ceil(50000/256) coarse buckets, 256 nodes each
#define CAP   5120       // per-bucket region capacity
#define CHUNK 2048       // edges per part1 block (2048 proven best: scatter-write granularity)
#define NPART1 ((NE + CHUNK - 1) / CHUNK)   // 391
#define NLIN1B ((NN + 127) / 128)           // 391  (fused linear1 grid, 32 rows/wave)
#define NAGG1  (NN / 16)                    // 3125 (fused agg1+linear2 grid, 16 nodes/block)
#define NPREP  160                          // 40960 / 256

typedef unsigned int uint;
typedef unsigned short ushort;
typedef __attribute__((ext_vector_type(8))) short short8;
typedef __attribute__((ext_vector_type(4))) float float4v;

__device__ __forceinline__ short f2bf(float f) {
    union { float f; unsigned u; } v; v.f = f;
    unsigned r = v.u + 0x7fffu + ((v.u >> 16) & 1u);   // round-to-nearest-even
    return (short)(r >> 16);
}
__device__ __forceinline__ float bflo(uint u) {
    union { uint u; float f; } v; v.u = u << 16; return v.f;
}
__device__ __forceinline__ float bfhi(uint u) {
    union { uint u; float f; } v; v.u = u & 0xffff0000u; return v.f;
}

// 256-thread block exclusive scan (ws = 4-int shared scratch). All 256 call.
__device__ __forceinline__ int excl_scan256(int v, int* ws) {
    int lane = threadIdx.x & 63, wv = threadIdx.x >> 6;
    int x = v;
    #pragma unroll
    for (int o = 1; o < 64; o <<= 1) {
        int y = __shfl_up(x, o);
        if (lane >= o) x += y;
    }
    if (lane == 63) ws[wv] = x;
    __syncthreads();
    int add = 0;
    #pragma unroll
    for (int w = 0; w < 4; w++) add += (w < wv) ? ws[w] : 0;
    return x + add - v;
}

// 512-thread block exclusive scan (ws = 8-int shared scratch). All 512 call.
__device__ __forceinline__ int excl_scan512(int v, int* ws) {
    int lane = threadIdx.x & 63, wv = threadIdx.x >> 6;   // wv in 0..7
    int x = v;
    #pragma unroll
    for (int o = 1; o < 64; o <<= 1) {
        int y = __shfl_up(x, o);
        if (lane >= o) x += y;
    }
    if (lane == 63) ws[wv] = x;
    __syncthreads();
    int add = 0;
    #pragma unroll
    for (int w = 0; w < 8; w++) add += (w < wv) ? ws[w] : 0;
    return x + add - v;
}

// ---------------- prep: weight transpose to MFMA B-fragment order + zero bcur ----------------
__global__ __launch_bounds__(256) void k_prep(const float* __restrict__ W1, const float* __restrict__ W2,
                                              short* __restrict__ W1f, short* __restrict__ W2f,
                                              int* __restrict__ bcur) {
    if (blockIdx.x == NPREP) {
        if (threadIdx.x < NBUCK) bcur[threadIdx.x] = 0;
        return;
    }
    int i = blockIdx.x * 256 + threadIdx.x;
    if (i < INF_ * HIDF) {
        int kk = i & 7, t = i >> 3;
        int m_l = t & 15, q = (t >> 4) & 3, s = t >> 6;
        int nb = s & 7, kc = s >> 3;
        int k = kc * 32 + q * 8 + kk, n = nb * 16 + m_l;
        W1f[i] = f2bf(W1[k * HIDF + n]);
    } else if (i < INF_ * HIDF + HIDF * OUTF) {
        int i2 = i - INF_ * HIDF;
        int kk = i2 & 7, t = i2 >> 3;
        int m_l = t & 15, q = (t >> 4) & 3, s = t >> 6;
        int nb = s & 3, kc = s >> 2;
        int k = kc * 32 + q * 8 + kk, n = nb * 16 + m_l;
        W2f[i2] = f2bf(W2[k * OUTF + n]);
    }
}

// ---------------- fused: part1 (coarse bucket sort) + linear1 (+s1 epilogue) ----------------

__global__ __launch_bounds__(256, 2) void k_f1(const int* __restrict__ src, const int* __restrict__ tgt,
                                               int* __restrict__ bcur, uint2* __restrict__ pairs,
                                               const float* __restrict__ X, const short* __restrict__ W1f,
                                               const float* __restrict__ b1, ushort* __restrict__ Hb,
                                               const float* __restrict__ a1w, float* __restrict__ s1s,
                                               float* __restrict__ s1t) {
    if (blockIdx.x < NPART1) {
        // ================= part1 =================
        __shared__ int hist[NBUCK], lofs[NBUCK], cur[NBUCK], gstart[NBUCK];
        __shared__ int ws[4];
        __shared__ int ltgt[CHUNK], lsrc[CHUNK];
        int tid = threadIdx.x;
        for (int i = tid; i < NBUCK; i += 256) hist[i] = 0;
        __syncthreads();

        int base = blockIdx.x * CHUNK;
        int cnt = NE - base; if (cnt > CHUNK) cnt = CHUNK;

        int t_[8], s_[8];
        #pragma unroll
        for (int k = 0; k < 8; k++) {
            int idx = k * 256 + tid;
            if (idx < cnt) {
                int j = base + idx;
                t_[k] = tgt[j]; s_[k] = src[j];
                atomicAdd(&hist[t_[k] >> 8], 1);
            } else t_[k] = -1;
        }
        __syncthreads();

        int v = (tid < NBUCK) ? hist[tid] : 0;
        int excl = excl_scan256(v, ws);
        if (tid < NBUCK) {
            lofs[tid] = excl;
            cur[tid] = excl;
            gstart[tid] = atomicAdd(&bcur[tid], v);
        }
        __syncthreads();

        #pragma unroll
        for (int k = 0; k < 8; k++) {
            if (t_[k] >= 0) {
                int b = t_[k] >> 8;
                int pos = atomicAdd(&cur[b], 1);
                ltgt[pos] = t_[k]; lsrc[pos] = s_[k];
            }
        }
        __syncthreads();

        for (int j = tid; j < cnt; j += 256) {
            int tv = ltgt[j];
            int b = tv >> 8;
            int dst = gstart[b] + (j - lofs[b]);
            pairs[(size_t)b * CAP + dst] = make_uint2((uint)tv, (uint)lsrc[j]);
        }
        return;
    }
    // ================= linear1 + s1 : 32 rows per wave (2 MFMA A-tiles) =================
    // kc-level double-buffer: issue next kc's A+B loads before current kc's MFMAs (12 loads in flight).
    int bid = blockIdx.x - NPART1;
    int w = threadIdx.x >> 6;
    int l = threadIdx.x & 63;
    int m_l = l & 15, q = l >> 4;
    int row0 = bid * 128 + w * 32;
    int rA0 = row0 + m_l;
    int rA1 = row0 + 16 + m_l;
    int rc0 = rA0 < NN ? rA0 : NN - 1;
    int rc1 = rA1 < NN ? rA1 : NN - 1;
    const float* pa0 = X + (size_t)rc0 * INF_ + q * 8;
    const float* pa1 = X + (size_t)rc1 * INF_ + q * 8;
    const short8* Bp = (const short8*)W1f;

    float4 xu[2][4];
    short8 bb[2][8];
    xu[0][0] = *(const float4*)(pa0);
    xu[0][1] = *(const float4*)(pa0 + 4);
    xu[0][2] = *(const float4*)(pa1);
    xu[0][3] = *(const float4*)(pa1 + 4);
    #pragma unroll
    for (int n = 0; n < 8; n++) bb[0][n] = Bp[n * 64 + l];

    float4v acc0[8] = {}, acc1[8] = {};
    #pragma unroll
    for (int kc = 0; kc < 8; kc++) {
        const int cur_ = kc & 1, nxt = cur_ ^ 1;
        if (kc < 7) {
            xu[nxt][0] = *(const float4*)(pa0 + (kc + 1) * 32);
            xu[nxt][1] = *(const float4*)(pa0 + (kc + 1) * 32 + 4);
            xu[nxt][2] = *(const float4*)(pa1 + (kc + 1) * 32);
            xu[nxt][3] = *(const float4*)(pa1 + (kc + 1) * 32 + 4);
            #pragma unroll
            for (int n = 0; n < 8; n++) bb[nxt][n] = Bp[((kc + 1) * 8 + n) * 64 + l];
        }
        float4 u0 = xu[cur_][0], u1 = xu[cur_][1], v0 = xu[cur_][2], v1 = xu[cur_][3];
        short8 af0, af1;
        af0[0] = f2bf(u0.x); af0[1] = f2bf(u0.y); af0[2] = f2bf(u0.z); af0[3] = f2bf(u0.w);
        af0[4] = f2bf(u1.x); af0[5] = f2bf(u1.y); af0[6] = f2bf(u1.z); af0[7] = f2bf(u1.w);
        af1[0] = f2bf(v0.x); af1[1] = f2bf(v0.y); af1[2] = f2bf(v0.z); af1[3] = f2bf(v0.w);
        af1[4] = f2bf(v1.x); af1[5] = f2bf(v1.y); af1[6] = f2bf(v1.z); af1[7] = f2bf(v1.w);
        #pragma unroll
        for (int n = 0; n < 8; n++) {
            acc0[n] = __builtin_amdgcn_mfma_f32_16x16x32_bf16(af0, bb[cur_][n], acc0[n], 0, 0, 0);
            acc1[n] = __builtin_amdgcn_mfma_f32_16x16x32_bf16(af1, bb[cur_][n], acc1[n], 0, 0, 0);
        }
    }

    float vs_r[8], vt_r[8];
    #pragma unroll
    for (int r = 0; r < 8; r++) { vs_r[r] = 0.f; vt_r[r] = 0.f; }
    #pragma unroll
    for (int n = 0; n < 8; n++) {
        int col = n * 16 + m_l;
        float bias = b1[col];
        float aw0 = a1w[col], aw1 = a1w[HIDF + col];
        #pragma unroll
        for (int r = 0; r < 4; r++) {
            int row = row0 + q * 4 + r;
            float v = acc0[n][r] + bias;
            v = v > 0.f ? v : expm1f(v);   // elu
            vs_r[r] += v * aw0; vt_r[r] += v * aw1;
            if (row < NN) Hb[(size_t)row * HIDF + col] = (ushort)f2bf(v);

            int row1 = row0 + 16 + q * 4 + r;
            float v1 = acc1[n][r] + bias;
            v1 = v1 > 0.f ? v1 : expm1f(v1);   // elu
            vs_r[4 + r] += v1 * aw0; vt_r[4 + r] += v1 * aw1;
            if (row1 < NN) Hb[(size_t)row1 * HIDF + col] = (ushort)f2bf(v1);
        }
    }
    #pragma unroll
    for (int r = 0; r < 8; r++) {
        #pragma unroll
        for (int o = 1; o < 16; o <<= 1) {
            vs_r[r] += __shfl_xor(vs_r[r], o);
            vt_r[r] += __shfl_xor(vt_r[r], o);
        }
    }
    if (m_l == 0) {
        #pragma unroll
        for (int r = 0; r < 4; r++) {
            int row = row0 + q * 4 + r;
            if (row < NN) { s1s[row] = vs_r[r]; s1t[row] = vt_r[r]; }
            int row1 = row0 + 16 + q * 4 + r;
            if (row1 < NN) { s1s[row1] = vs_r[4 + r]; s1t[row1] = vt_r[4 + r]; }
        }
    }
}

// ---------------- part2: fine sort within bucket (512 threads: better CU fill at 196 blocks) ----------------
__global__ __launch_bounds__(512) void k_part2(const int* __restrict__ bcur, const uint2* __restrict__ pairs,
                                               int* __restrict__ fsrc, int* __restrict__ nbeg,
                                               int* __restrict__ ncnt) {
    __shared__ int hist[256], cur[256];
    __shared__ int ws[8];
    int tid = threadIdx.x;
    int b = blockIdx.x;
    int cnt = __builtin_amdgcn_readfirstlane(bcur[b]);
    if (tid < 256) hist[tid] = 0;
    __syncthreads();

    const uint2* pb = pairs + (size_t)b * CAP;
    for (int j = tid; j < cnt; j += 512) {
        uint2 e = pb[j];
        atomicAdd(&hist[e.x & 255], 1);
    }
    __syncthreads();

    int v = (tid < 256) ? hist[tid] : 0;
    int excl = excl_scan512(v, ws);
    if (tid < 256) {
        int node = (b << 8) + tid;
        if (node < NN) { nbeg[node] = b * CAP + excl; ncnt[node] = v; }
        cur[tid] = excl;
    }
    __syncthreads();

    for (int j = tid; j < cnt; j += 512) {
        uint2 e = pb[j];
        int pos = atomicAdd(&cur[e.x & 255], 1);
        fsrc[(size_t)b * CAP + pos] = (int)e.y;
    }
}

// ---------------- fused agg1 (softmax+gather) + linear2 + s2 epilogue ----------------
// 16 nodes per 256-thread block. Gather vectorized: 16 lanes x 16B (dwordx4) per 256B row,
// so one wave-load fetches 4 edges' rows; quarter q4=lane>>4 owns edge j+q4.
// Then each wave computes one 16-col slice of the 16x128 @ 128x64 MFMA matmul.

__global__ __launch_bounds__(256) void k_agg1l2(const uint4* __restrict__ Hb16, const int* __restrict__ nbeg,
                                                const int* __restrict__ ncnt, const int* __restrict__ fsrc,
                                                const float* __restrict__ ss, const float* __restrict__ st_,
                                                const float* __restrict__ ab,
                                                const short* __restrict__ W2f, const float* __restrict__ b2,
                                                const float* __restrict__ a2w,
                                                ushort* __restrict__ Ob, float* __restrict__ s2s,
                                                float* __restrict__ s2t) {
    __shared__ uint tile[16 * 72];           // 16 rows x 64 dwords, +8 pad (288B stride, 16B-aligned rows)
    __shared__ float sAcc[4][16], sTcc[4][16];
    int wv   = threadIdx.x >> 6;
    int lane = threadIdx.x & 63;
    int q4 = lane >> 4, fi = lane & 15;

    #pragma unroll 1
    for (int it = 0; it < 4; ++it) {
        int wid = blockIdx.x * 16 + wv * 4 + it;   // grid exact: always < NN
        int beg = __builtin_amdgcn_readfirstlane(nbeg[wid]);
        int deg = __builtin_amdgcn_readfirstlane(ncnt[wid]);
        int end = beg + deg;
        float bias = ab[0] + st_[wid];
        float f[8];
        #pragma unroll
        for (int k = 0; k < 8; k++) f[k] = 0.f;

        if (deg > 0 && deg <= 64) {
            int my_s = 0; float a = -INFINITY;
            if (lane < deg) {
                my_s = fsrc[beg + lane];
                float t = ss[my_s] + bias;
                a = t >= 0.f ? t : 0.2f * t;
            }
            float m = a;
            #pragma unroll
            for (int o = 32; o > 0; o >>= 1) m = fmaxf(m, __shfl_xor(m, o));
            float e = (lane < deg) ? __expf(a - m) : 0.f;
            float sum = e;
            #pragma unroll
            for (int o = 32; o > 0; o >>= 1) sum += __shfl_xor(sum, o);
            float p = e * (1.f / (sum + 1e-16f));
            int ngroups = (deg + 3) >> 2;        // wave-uniform; edges beyond deg carry p=0
            int s0 = __shfl(my_s, q4); float w0 = __shfl(p, q4);
            uint4 x0 = Hb16[(size_t)s0 * 16 + fi];
            for (int g = 1; g < ngroups; g++) {
                int ei = g * 4 + q4;
                int s1 = __shfl(my_s, ei); float w1 = __shfl(p, ei);
                uint4 x1 = Hb16[(size_t)s1 * 16 + fi];
                f[0] += w0 * bflo(x0.x); f[1] += w0 * bfhi(x0.x);
                f[2] += w0 * bflo(x0.y); f[3] += w0 * bfhi(x0.y);
                f[4] += w0 * bflo(x0.z); f[5] += w0 * bfhi(x0.z);
                f[6] += w0 * bflo(x0.w); f[7] += w0 * bfhi(x0.w);
                x0 = x1; w0 = w1;
            }
            f[0] += w0 * bflo(x0.x); f[1] += w0 * bfhi(x0.x);
            f[2] += w0 * bflo(x0.y); f[3] += w0 * bfhi(x0.y);
            f[4] += w0 * bflo(x0.z); f[5] += w0 * bfhi(x0.z);
            f[6] += w0 * bflo(x0.w); f[7] += w0 * bfhi(x0.w);
        } else if (deg > 64) {
            float m = -INFINITY;
            for (int i = beg + lane; i < end; i += 64) {
                float t = ss[fsrc[i]] + bias;
                t = t >= 0.f ? t : 0.2f * t;
                m = fmaxf(m, t);
            }
            #pragma unroll
            for (int o = 32; o > 0; o >>= 1) m = fmaxf(m, __shfl_xor(m, o));
            float sum = 0.f;
            for (int i = beg + lane; i < end; i += 64) {
                float t = ss[fsrc[i]] + bias;
                t = t >= 0.f ? t : 0.2f * t;
                sum += __expf(t - m);
            }
            #pragma unroll
            for (int o = 32; o > 0; o >>= 1) sum += __shfl_xor(sum, o);
            float inv = 1.f / (sum + 1e-16f);
            for (int c = beg; c < end; c += 64) {
                int cnt = min(64, end - c);
                int my_s = 0; float p = 0.f;
                if (lane < cnt) {
                    my_s = fsrc[c + lane];
                    float t = ss[my_s] + bias;
                    t = t >= 0.f ? t : 0.2f * t;
                    p = __expf(t - m) * inv;
                }
                int ngroups = (cnt + 3) >> 2;
                for (int g = 0; g < ngroups; g++) {
                    int ei = g * 4 + q4;
                    int s1 = __shfl(my_s, ei); float w1 = __shfl(p, ei);
                    uint4 x1 = Hb16[(size_t)s1 * 16 + fi];
                    f[0] += w1 * bflo(x1.x); f[1] += w1 * bfhi(x1.x);
                    f[2] += w1 * bflo(x1.y); f[3] += w1 * bfhi(x1.y);
                    f[4] += w1 * bflo(x1.z); f[5] += w1 * bfhi(x1.z);
                    f[6] += w1 * bflo(x1.w); f[7] += w1 * bfhi(x1.w);
                }
            }
        }
        // cross-quarter reduction: quarters hold partial sums of the same features
        #pragma unroll
        for (int k = 0; k < 8; k++) {
            f[k] += __shfl_xor(f[k], 16);
            f[k] += __shfl_xor(f[k], 32);
        }
        if (q4 == 0) {
            uint d0 = (uint)(ushort)f2bf(f[0]) | ((uint)(ushort)f2bf(f[1]) << 16);
            uint d1 = (uint)(ushort)f2bf(f[2]) | ((uint)(ushort)f2bf(f[3]) << 16);
            uint d2 = (uint)(ushort)f2bf(f[4]) | ((uint)(ushort)f2bf(f[5]) << 16);
            uint d3 = (uint)(ushort)f2bf(f[6]) | ((uint)(ushort)f2bf(f[7]) << 16);
            *(uint4*)&tile[(wv * 4 + it) * 72 + fi * 4] = make_uint4(d0, d1, d2, d3);
        }
    }
    __syncthreads();

    // ---- linear2 on the 16x128 LDS tile: wave wv computes cols wv*16..wv*16+15 ----
    int m_l = lane & 15, q = lane >> 4;
    const short8* Bp = (const short8*)W2f;
    float4v acc = {};
    #pragma unroll
    for (int kc = 0; kc < 4; kc++) {
        // A-frag: row m_l, bf16 elems kc*32+q*8.. +7  ->  dwords kc*16+q*4.. +3
        short8 afr = *(const short8*)&tile[m_l * 72 + kc * 16 + q * 4];
        short8 b = Bp[(kc * 4 + wv) * 64 + lane];
        acc = __builtin_amdgcn_mfma_f32_16x16x32_bf16(afr, b, acc, 0, 0, 0);
    }
    int col = wv * 16 + m_l;
    float bias2 = b2[col];
    float aw0 = a2w[col], aw1 = a2w[OUTF + col];
    float vs_r[4], vt_r[4];
    #pragma unroll
    for (int r = 0; r < 4; r++) {
        int row = q * 4 + r;
        float v = acc[r] + bias2;
        vs_r[r] = v * aw0; vt_r[r] = v * aw1;
        Ob[(size_t)(blockIdx.x * 16 + row) * OUTF + col] = (ushort)f2bf(v);
    }
    #pragma unroll
    for (int r = 0; r < 4; r++) {
        #pragma unroll
        for (int o = 1; o < 16; o <<= 1) {
            vs_r[r] += __shfl_xor(vs_r[r], o);
            vt_r[r] += __shfl_xor(vt_r[r], o);
        }
    }
    if (m_l == 0) {
        #pragma unroll
        for (int r = 0; r < 4; r++) { sAcc[wv][q * 4 + r] = vs_r[r]; sTcc[wv][q * 4 + r] = vt_r[r]; }
    }
    __syncthreads();
    if (threadIdx.x < 16) {
        int row = threadIdx.x;
        s2s[blockIdx.x * 16 + row] = sAcc[0][row] + sAcc[1][row] + sAcc[2][row] + sAcc[3][row];
        s2t[blockIdx.x * 16 + row] = sTcc[0][row] + sTcc[1][row] + sTcc[2][row] + sTcc[3][row];
    }
}

// ---------------- agg2: softmax + gather + log_softmax output ----------------
// Gather vectorized: 8 lanes x 16B (dwordx4) per 128B row => 8 edges per wave-load.
// oct = lane>>3 owns edge j+oct; lane&7 owns features 8*(lane&7)..+7.

__global__ __launch_bounds__(256) void k_agg2f(const uint4* __restrict__ Ob16, const int* __restrict__ nbeg,
                                               const int* __restrict__ ncnt, const int* __restrict__ fsrc,
                                               const float* __restrict__ ss, const float* __restrict__ st_,
                                               const float* __restrict__ ab, float* __restrict__ out) {
    int wid  = (blockIdx.x * 256 + threadIdx.x) >> 6;
    int lane = threadIdx.x & 63;
    if (wid >= NN) return;
    int oct = lane >> 3, fi = lane & 7;
    int beg = __builtin_amdgcn_readfirstlane(nbeg[wid]);
    int deg = __builtin_amdgcn_readfirstlane(ncnt[wid]);
    int end = beg + deg;
    float bias = ab[0] + st_[wid];
    float f[8];
    #pragma unroll
    for (int k = 0; k < 8; k++) f[k] = 0.f;

    if (deg > 0 && deg <= 64) {
        int my_s = 0; float a = -INFINITY;
        if (lane < deg) {
            my_s = fsrc[beg + lane];
            float t = ss[my_s] + bias;
            a = t >= 0.f ? t : 0.2f * t;
        }
        float m = a;
        #pragma unroll
        for (int o = 32; o > 0; o >>= 1) m = fmaxf(m, __shfl_xor(m, o));
        float e = (lane < deg) ? __expf(a - m) : 0.f;
        float sum = e;
        #pragma unroll
        for (int o = 32; o > 0; o >>= 1) sum += __shfl_xor(sum, o);
        float p = e * (1.f / (sum + 1e-16f));
        int ngroups = (deg + 7) >> 3;        // edges beyond deg carry p=0
        int s0 = __shfl(my_s, oct); float w0 = __shfl(p, oct);
        uint4 x0 = Ob16[(size_t)s0 * 8 + fi];
        for (int g = 1; g < ngroups; g++) {
            int ei = g * 8 + oct;
            int s1 = __shfl(my_s, ei); float w1 = __shfl(p, ei);
            uint4 x1 = Ob16[(size_t)s1 * 8 + fi];
            f[0] += w0 * bflo(x0.x); f[1] += w0 * bfhi(x0.x);
            f[2] += w0 * bflo(x0.y); f[3] += w0 * bfhi(x0.y);
            f[4] += w0 * bflo(x0.z); f[5] += w0 * bfhi(x0.z);
            f[6] += w0 * bflo(x0.w); f[7] += w0 * bfhi(x0.w);
            x0 = x1; w0 = w1;
        }
        f[0] += w0 * bflo(x0.x); f[1] += w0 * bfhi(x0.x);
        f[2] += w0 * bflo(x0.y); f[3] += w0 * bfhi(x0.y);
        f[4] += w0 * bflo(x0.z); f[5] += w0 * bfhi(x0.z);
        f[6] += w0 * bflo(x0.w); f[7] += w0 * bfhi(x0.w);
    } else if (deg > 64) {
        float m = -INFINITY;
        for (int i = beg + lane; i < end; i += 64) {
            float t = ss[fsrc[i]] + bias;
            t = t >= 0.f ? t : 0.2f * t;
            m = fmaxf(m, t);
        }
        #pragma unroll
        for (int o = 32; o > 0; o >>= 1) m = fmaxf(m, __shfl_xor(m, o));
        float sum = 0.f;
        for (int i = beg + lane; i < end; i += 64) {
            float t = ss[fsrc[i]] + bias;
            t = t >= 0.f ? t : 0.2f * t;
            sum += __expf(t - m);
        }
        #pragma unroll
        for (int o = 32; o > 0; o >>= 1) sum += __shfl_xor(sum, o);
        float inv = 1.f / (sum + 1e-16f);
        for (int c = beg; c < end; c += 64) {
            int cnt = min(64, end - c);
            int my_s = 0; float p = 0.f;
            if (lane < cnt) {
                my_s = fsrc[c + lane];
                float t = ss[my_s] + bias;
                t = t >= 0.f ? t : 0.2f * t;
                p = __expf(t - m) * inv;
            }
            int ngroups = (cnt + 7) >> 3;
            for (int g = 0; g < ngroups; g++) {
                int ei = g * 8 + oct;
                int s1 = __shfl(my_s, ei); float w1 = __shfl(p, ei);
                uint4 x1 = Ob16[(size_t)s1 * 8 + fi];
                f[0] += w1 * bflo(x1.x); f[1] += w1 * bfhi(x1.x);
                f[2] += w1 * bflo(x1.y); f[3] += w1 * bfhi(x1.y);
                f[4] += w1 * bflo(x1.z); f[5] += w1 * bfhi(x1.z);
                f[6] += w1 * bflo(x1.w); f[7] += w1 * bfhi(x1.w);
            }
        }
    }
    // cross-oct reduction: octs hold partials of the same features
    #pragma unroll
    for (int k = 0; k < 8; k++) {
        f[k] += __shfl_xor(f[k], 8);
        f[k] += __shfl_xor(f[k], 16);
        f[k] += __shfl_xor(f[k], 32);
    }
    // log_softmax over 64 features: lane fi owns features 8*fi..8*fi+7 (replicated across octs)
    float mx = f[0];
    #pragma unroll
    for (int k = 1; k < 8; k++) mx = fmaxf(mx, f[k]);
    #pragma unroll
    for (int o = 1; o < 8; o <<= 1) mx = fmaxf(mx, __shfl_xor(mx, o));
    float es = 0.f;
    #pragma unroll
    for (int k = 0; k < 8; k++) es += __expf(f[k] - mx);
    #pragma unroll
    for (int o = 1; o < 8; o <<= 1) es += __shfl_xor(es, o);
    float lg = __logf(es) + mx;
    if (oct == 0) {
        float4 r0, r1;
        r0.x = f[0] - lg; r0.y = f[1] - lg; r0.z = f[2] - lg; r0.w = f[3] - lg;
        r1.x = f[4] - lg; r1.y = f[5] - lg; r1.z = f[6] - lg; r1.w = f[7] - lg;
        float4* po = (float4*)(out + (size_t)wid * 64 + fi * 8);
        po[0] = r0; po[1] = r1;
    }
}

// ---------------- launcher ----------------

extern "C" void kernel_launch(void* const* d_in, const int* in_sizes, int n_in,
                              void* d_out, int out_size, void* d_ws, size_t ws_size,
                              hipStream_t stream) {
    const float* X   = (const float*)d_in[0];
    const int*   ei  = (const int*)d_in[1];
    const float* W1  = (const float*)d_in[2];
    const float* b1  = (const float*)d_in[3];
    const float* a1w = (const float*)d_in[4];
    const float* a1b = (const float*)d_in[5];
    const float* W2  = (const float*)d_in[6];
    const float* b2  = (const float*)d_in[7];
    const float* a2w = (const float*)d_in[8];
    const float* a2b = (const float*)d_in[9];
    const int* src = ei;           // edge_index[0]
    const int* tgt = ei + NE;      // edge_index[1]

    char* p = (char*)d_ws;
    size_t off = 0;
    auto alloc = [&](size_t bytes) -> char* {
        char* r = p + off;
        off = (off + bytes + 255) & ~(size_t)255;
        return r;
    };
    ushort* Hb    = (ushort*)alloc((size_t)NN * HIDF * 2);
    ushort* Ob    = (ushort*)alloc((size_t)NN * OUTF * 2);
    short* W1f    = (short*)alloc((size_t)INF_ * HIDF * 2);
    short* W2f    = (short*)alloc((size_t)HIDF * OUTF * 2);
    float* s1s    = (float*)alloc((size_t)NN * 4);
    float* s1t    = (float*)alloc((size_t)NN * 4);
    float* s2s    = (float*)alloc((size_t)NN * 4);
    float* s2t    = (float*)alloc((size_t)NN * 4);
    int*   bcur   = (int*)alloc((size_t)NBUCK * 4);
    uint2* pairs  = (uint2*)alloc((size_t)NBUCK * CAP * 8);
    int*   fsrc   = (int*)alloc((size_t)NBUCK * CAP * 4);
    int*   nbeg   = (int*)alloc((size_t)NN * 4);
    int*   ncnt   = (int*)alloc((size_t)NN * 4);

    k_prep   <<<NPREP + 1, 256, 0, stream>>>(W1, W2, W1f, W2f, bcur);
    k_f1     <<<NPART1 + NLIN1B, 256, 0, stream>>>(src, tgt, bcur, pairs,
                                                   X, W1f, b1, Hb, a1w, s1s, s1t);
    k_part2  <<<NBUCK, 512, 0, stream>>>(bcur, pairs, fsrc, nbeg, ncnt);
    k_agg1l2 <<<NAGG1, 256, 0, stream>>>((const uint4*)Hb, nbeg, ncnt, fsrc, s1s, s1t, a1b,
                                         W2f, b2, a2w, Ob, s2s, s2t);
    k_agg2f  <<<NN / 4, 256, 0, stream>>>((const uint4*)Ob, nbeg, ncnt, fsrc, s2s, s2t, a2b, (float*)d_out);
}

// Round 10
// 207.719 us; speedup vs baseline: 1.0112x; 1.0112x over previous
//
#include <hip/hip_runtime.h>

#define NN    50000
#define NE    800000
#define INF_  256
#define HIDF  128
#define OUTF  64
#define NBUCK 196        // ceil(50000/256) coarse buckets, 256 nodes each
#define CAP   5120       // per-bucket region capacity
#define CHUNK 2048       // edges per part1 block (2048 proven best: scatter-write granularity)
#define NPART1 ((NE + CHUNK - 1) / CHUNK)   // 391
#define NLIN1B ((NN + 127) / 128)           // 391  (fused linear1 grid, 32 rows/wave)
#define NAGG1  (NN / 16)                    // 3125 (fused agg1+linear2 grid, 16 nodes/block)
#define NPREP  160                          // 40960 / 256

typedef unsigned int uint;
typedef unsigned short ushort;
typedef __attribute__((ext_vector_type(8))) short short8;
typedef __attribute__((ext_vector_type(4))) float float4v;

__device__ __forceinline__ short f2bf(float f) {
    union { float f; unsigned u; } v; v.f = f;
    unsigned r = v.u + 0x7fffu + ((v.u >> 16) & 1u);   // round-to-nearest-even
    return (short)(r >> 16);
}
__device__ __forceinline__ float bflo(uint u) {
    union { uint u; float f; } v; v.u = u << 16; return v.f;
}
__device__ __forceinline__ float bfhi(uint u) {
    union { uint u; float f; } v; v.u = u & 0xffff0000u; return v.f;
}

// 256-thread block exclusive scan (ws = 4-int shared scratch). All 256 call.
__device__ __forceinline__ int excl_scan256(int v, int* ws) {
    int lane = threadIdx.x & 63, wv = threadIdx.x >> 6;
    int x = v;
    #pragma unroll
    for (int o = 1; o < 64; o <<= 1) {
        int y = __shfl_up(x, o);
        if (lane >= o) x += y;
    }
    if (lane == 63) ws[wv] = x;
    __syncthreads();
    int add = 0;
    #pragma unroll
    for (int w = 0; w < 4; w++) add += (w < wv) ? ws[w] : 0;
    return x + add - v;
}

// 512-thread block exclusive scan (ws = 8-int shared scratch). All 512 call.
__device__ __forceinline__ int excl_scan512(int v, int* ws) {
    int lane = threadIdx.x & 63, wv = threadIdx.x >> 6;   // wv in 0..7
    int x = v;
    #pragma unroll
    for (int o = 1; o < 64; o <<= 1) {
        int y = __shfl_up(x, o);
        if (lane >= o) x += y;
    }
    if (lane == 63) ws[wv] = x;
    __syncthreads();
    int add = 0;
    #pragma unroll
    for (int w = 0; w < 8; w++) add += (w < wv) ? ws[w] : 0;
    return x + add - v;
}

// ---------------- prep: weight transpose to MFMA B-fragment order + zero bcur ----------------
__global__ __launch_bounds__(256) void k_prep(const float* __restrict__ W1, const float* __restrict__ W2,
                                              short* __restrict__ W1f, short* __restrict__ W2f,
                                              int* __restrict__ bcur) {
    if (blockIdx.x == NPREP) {
        if (threadIdx.x < NBUCK) bcur[threadIdx.x] = 0;
        return;
    }
    int i = blockIdx.x * 256 + threadIdx.x;
    if (i < INF_ * HIDF) {
        int kk = i & 7, t = i >> 3;
        int m_l = t & 15, q = (t >> 4) & 3, s = t >> 6;
        int nb = s & 7, kc = s >> 3;
        int k = kc * 32 + q * 8 + kk, n = nb * 16 + m_l;
        W1f[i] = f2bf(W1[k * HIDF + n]);
    } else if (i < INF_ * HIDF + HIDF * OUTF) {
        int i2 = i - INF_ * HIDF;
        int kk = i2 & 7, t = i2 >> 3;
        int m_l = t & 15, q = (t >> 4) & 3, s = t >> 6;
        int nb = s & 3, kc = s >> 2;
        int k = kc * 32 + q * 8 + kk, n = nb * 16 + m_l;
        W2f[i2] = f2bf(W2[k * OUTF + n]);
    }
}

// ---------------- fused: part1 (coarse bucket sort, PACKED pairs) + linear1 (+s1 epilogue) ----------------
// tgt,src < 50000 < 2^16: pack (tgt<<16)|src into one uint -> halves scatter bytes.

__global__ __launch_bounds__(256, 2) void k_f1(const int* __restrict__ src, const int* __restrict__ tgt,
                                               int* __restrict__ bcur, uint* __restrict__ pairs,
                                               const float* __restrict__ X, const short* __restrict__ W1f,
                                               const float* __restrict__ b1, ushort* __restrict__ Hb,
                                               const float* __restrict__ a1w, float* __restrict__ s1s,
                                               float* __restrict__ s1t) {
    if (blockIdx.x < NPART1) {
        // ================= part1 =================
        __shared__ int hist[NBUCK], lofs[NBUCK], cur[NBUCK], gstart[NBUCK];
        __shared__ int ws[4];
        __shared__ uint lpack[CHUNK];
        int tid = threadIdx.x;
        for (int i = tid; i < NBUCK; i += 256) hist[i] = 0;
        __syncthreads();

        int base = blockIdx.x * CHUNK;
        int cnt = NE - base; if (cnt > CHUNK) cnt = CHUNK;

        int t_[8], s_[8];
        #pragma unroll
        for (int k = 0; k < 8; k++) {
            int idx = k * 256 + tid;
            if (idx < cnt) {
                int j = base + idx;
                t_[k] = tgt[j]; s_[k] = src[j];
                atomicAdd(&hist[t_[k] >> 8], 1);
            } else t_[k] = -1;
        }
        __syncthreads();

        int v = (tid < NBUCK) ? hist[tid] : 0;
        int excl = excl_scan256(v, ws);
        if (tid < NBUCK) {
            lofs[tid] = excl;
            cur[tid] = excl;
            gstart[tid] = atomicAdd(&bcur[tid], v);
        }
        __syncthreads();

        #pragma unroll
        for (int k = 0; k < 8; k++) {
            if (t_[k] >= 0) {
                int b = t_[k] >> 8;
                int pos = atomicAdd(&cur[b], 1);
                lpack[pos] = ((uint)t_[k] << 16) | (uint)s_[k];
            }
        }
        __syncthreads();

        for (int j = tid; j < cnt; j += 256) {
            uint pk = lpack[j];
            int b = pk >> 24;                 // tgt>>8
            int dst = gstart[b] + (j - lofs[b]);
            pairs[(size_t)b * CAP + dst] = pk;
        }
        return;
    }
    // ================= linear1 + s1 : 32 rows per wave (2 MFMA A-tiles) =================
    int bid = blockIdx.x - NPART1;
    int w = threadIdx.x >> 6;
    int l = threadIdx.x & 63;
    int m_l = l & 15, q = l >> 4;
    int row0 = bid * 128 + w * 32;
    int rA0 = row0 + m_l;
    int rA1 = row0 + 16 + m_l;
    int rc0 = rA0 < NN ? rA0 : NN - 1;
    int rc1 = rA1 < NN ? rA1 : NN - 1;
    const float* pa0 = X + (size_t)rc0 * INF_ + q * 8;
    const float* pa1 = X + (size_t)rc1 * INF_ + q * 8;
    const short8* Bp = (const short8*)W1f;

    float4 xu[2][4];
    short8 bb[2][8];
    xu[0][0] = *(const float4*)(pa0);
    xu[0][1] = *(const float4*)(pa0 + 4);
    xu[0][2] = *(const float4*)(pa1);
    xu[0][3] = *(const float4*)(pa1 + 4);
    #pragma unroll
    for (int n = 0; n < 8; n++) bb[0][n] = Bp[n * 64 + l];

    float4v acc0[8] = {}, acc1[8] = {};
    #pragma unroll
    for (int kc = 0; kc < 8; kc++) {
        const int cur_ = kc & 1, nxt = cur_ ^ 1;
        if (kc < 7) {
            xu[nxt][0] = *(const float4*)(pa0 + (kc + 1) * 32);
            xu[nxt][1] = *(const float4*)(pa0 + (kc + 1) * 32 + 4);
            xu[nxt][2] = *(const float4*)(pa1 + (kc + 1) * 32);
            xu[nxt][3] = *(const float4*)(pa1 + (kc + 1) * 32 + 4);
            #pragma unroll
            for (int n = 0; n < 8; n++) bb[nxt][n] = Bp[((kc + 1) * 8 + n) * 64 + l];
        }
        float4 u0 = xu[cur_][0], u1 = xu[cur_][1], v0 = xu[cur_][2], v1 = xu[cur_][3];
        short8 af0, af1;
        af0[0] = f2bf(u0.x); af0[1] = f2bf(u0.y); af0[2] = f2bf(u0.z); af0[3] = f2bf(u0.w);
        af0[4] = f2bf(u1.x); af0[5] = f2bf(u1.y); af0[6] = f2bf(u1.z); af0[7] = f2bf(u1.w);
        af1[0] = f2bf(v0.x); af1[1] = f2bf(v0.y); af1[2] = f2bf(v0.z); af1[3] = f2bf(v0.w);
        af1[4] = f2bf(v1.x); af1[5] = f2bf(v1.y); af1[6] = f2bf(v1.z); af1[7] = f2bf(v1.w);
        #pragma unroll
        for (int n = 0; n < 8; n++) {
            acc0[n] = __builtin_amdgcn_mfma_f32_16x16x32_bf16(af0, bb[cur_][n], acc0[n], 0, 0, 0);
            acc1[n] = __builtin_amdgcn_mfma_f32_16x16x32_bf16(af1, bb[cur_][n], acc1[n], 0, 0, 0);
        }
    }

    float vs_r[8], vt_r[8];
    #pragma unroll
    for (int r = 0; r < 8; r++) { vs_r[r] = 0.f; vt_r[r] = 0.f; }
    #pragma unroll
    for (int n = 0; n < 8; n++) {
        int col = n * 16 + m_l;
        float bias = b1[col];
        float aw0 = a1w[col], aw1 = a1w[HIDF + col];
        #pragma unroll
        for (int r = 0; r < 4; r++) {
            int row = row0 + q * 4 + r;
            float v = acc0[n][r] + bias;
            v = v > 0.f ? v : expm1f(v);   // elu
            vs_r[r] += v * aw0; vt_r[r] += v * aw1;
            if (row < NN) Hb[(size_t)row * HIDF + col] = (ushort)f2bf(v);

            int row1 = row0 + 16 + q * 4 + r;
            float v1 = acc1[n][r] + bias;
            v1 = v1 > 0.f ? v1 : expm1f(v1);   // elu
            vs_r[4 + r] += v1 * aw0; vt_r[4 + r] += v1 * aw1;
            if (row1 < NN) Hb[(size_t)row1 * HIDF + col] = (ushort)f2bf(v1);
        }
    }
    #pragma unroll
    for (int r = 0; r < 8; r++) {
        #pragma unroll
        for (int o = 1; o < 16; o <<= 1) {
            vs_r[r] += __shfl_xor(vs_r[r], o);
            vt_r[r] += __shfl_xor(vt_r[r], o);
        }
    }
    if (m_l == 0) {
        #pragma unroll
        for (int r = 0; r < 4; r++) {
            int row = row0 + q * 4 + r;
            if (row < NN) { s1s[row] = vs_r[r]; s1t[row] = vt_r[r]; }
            int row1 = row0 + 16 + q * 4 + r;
            if (row1 < NN) { s1s[row1] = vs_r[4 + r]; s1t[row1] = vt_r[4 + r]; }
        }
    }
}

// ---------------- part2: fine sort within bucket (512 threads; packed pairs) ----------------
__global__ __launch_bounds__(512) void k_part2(const int* __restrict__ bcur, const uint* __restrict__ pairs,
                                               int* __restrict__ fsrc, int* __restrict__ nbeg,
                                               int* __restrict__ ncnt) {
    __shared__ int hist[256], cur[256];
    __shared__ int ws[8];
    int tid = threadIdx.x;
    int b = blockIdx.x;
    int cnt = __builtin_amdgcn_readfirstlane(bcur[b]);
    if (tid < 256) hist[tid] = 0;
    __syncthreads();

    const uint* pb = pairs + (size_t)b * CAP;
    for (int j = tid; j < cnt; j += 512) {
        uint e = pb[j];
        atomicAdd(&hist[(e >> 16) & 255], 1);
    }
    __syncthreads();

    int v = (tid < 256) ? hist[tid] : 0;
    int excl = excl_scan512(v, ws);
    if (tid < 256) {
        int node = (b << 8) + tid;
        if (node < NN) { nbeg[node] = b * CAP + excl; ncnt[node] = v; }
        cur[tid] = excl;
    }
    __syncthreads();

    for (int j = tid; j < cnt; j += 512) {
        uint e = pb[j];
        int pos = atomicAdd(&cur[(e >> 16) & 255], 1);
        fsrc[(size_t)b * CAP + pos] = (int)(e & 0xFFFFu);
    }
}

// ---------------- fused agg1 (softmax+gather) + linear2 + s2 epilogue ----------------
// 16 nodes per 256-thread block. Gather vectorized: 16 lanes x 16B (dwordx4) per 256B row,
// so one wave-load fetches 4 edges' rows; quarter q4=lane>>4 owns edge j+q4.
// Then each wave computes one 16-col slice of the 16x128 @ 128x64 MFMA matmul.

__global__ __launch_bounds__(256) void k_agg1l2(const uint4* __restrict__ Hb16, const int* __restrict__ nbeg,
                                                const int* __restrict__ ncnt, const int* __restrict__ fsrc,
                                                const float* __restrict__ ss, const float* __restrict__ st_,
                                                const float* __restrict__ ab,
                                                const short* __restrict__ W2f, const float* __restrict__ b2,
                                                const float* __restrict__ a2w,
                                                ushort* __restrict__ Ob, float* __restrict__ s2s,
                                                float* __restrict__ s2t) {
    __shared__ uint tile[16 * 72];           // 16 rows x 64 dwords, +8 pad (288B stride, 16B-aligned rows)
    __shared__ float sAcc[4][16], sTcc[4][16];
    int wv   = threadIdx.x >> 6;
    int lane = threadIdx.x & 63;
    int q4 = lane >> 4, fi = lane & 15;

    #pragma unroll 1
    for (int it = 0; it < 4; ++it) {
        int wid = blockIdx.x * 16 + wv * 4 + it;   // grid exact: always < NN
        int beg = __builtin_amdgcn_readfirstlane(nbeg[wid]);
        int deg = __builtin_amdgcn_readfirstlane(ncnt[wid]);
        int end = beg + deg;
        float bias = ab[0] + st_[wid];
        float f[8];
        #pragma unroll
        for (int k = 0; k < 8; k++) f[k] = 0.f;

        if (deg > 0 && deg <= 64) {
            int my_s = 0; float a = -INFINITY;
            if (lane < deg) {
                my_s = fsrc[beg + lane];
                float t = ss[my_s] + bias;
                a = t >= 0.f ? t : 0.2f * t;
            }
            float m = a;
            #pragma unroll
            for (int o = 32; o > 0; o >>= 1) m = fmaxf(m, __shfl_xor(m, o));
            float e = (lane < deg) ? __expf(a - m) : 0.f;
            float sum = e;
            #pragma unroll
            for (int o = 32; o > 0; o >>= 1) sum += __shfl_xor(sum, o);
            float p = e * (1.f / (sum + 1e-16f));
            int ngroups = (deg + 3) >> 2;        // wave-uniform; edges beyond deg carry p=0
            int s0 = __shfl(my_s, q4); float w0 = __shfl(p, q4);
            uint4 x0 = Hb16[(size_t)s0 * 16 + fi];
            for (int g = 1; g < ngroups; g++) {
                int ei = g * 4 + q4;
                int s1 = __shfl(my_s, ei); float w1 = __shfl(p, ei);
                uint4 x1 = Hb16[(size_t)s1 * 16 + fi];
                f[0] += w0 * bflo(x0.x); f[1] += w0 * bfhi(x0.x);
                f[2] += w0 * bflo(x0.y); f[3] += w0 * bfhi(x0.y);
                f[4] += w0 * bflo(x0.z); f[5] += w0 * bfhi(x0.z);
                f[6] += w0 * bflo(x0.w); f[7] += w0 * bfhi(x0.w);
                x0 = x1; w0 = w1;
            }
            f[0] += w0 * bflo(x0.x); f[1] += w0 * bfhi(x0.x);
            f[2] += w0 * bflo(x0.y); f[3] += w0 * bfhi(x0.y);
            f[4] += w0 * bflo(x0.z); f[5] += w0 * bfhi(x0.z);
            f[6] += w0 * bflo(x0.w); f[7] += w0 * bfhi(x0.w);
        } else if (deg > 64) {
            float m = -INFINITY;
            for (int i = beg + lane; i < end; i += 64) {
                float t = ss[fsrc[i]] + bias;
                t = t >= 0.f ? t : 0.2f * t;
                m = fmaxf(m, t);
            }
            #pragma unroll
            for (int o = 32; o > 0; o >>= 1) m = fmaxf(m, __shfl_xor(m, o));
            float sum = 0.f;
            for (int i = beg + lane; i < end; i += 64) {
                float t = ss[fsrc[i]] + bias;
                t = t >= 0.f ? t : 0.2f * t;
                sum += __expf(t - m);
            }
            #pragma unroll
            for (int o = 32; o > 0; o >>= 1) sum += __shfl_xor(sum, o);
            float inv = 1.f / (sum + 1e-16f);
            for (int c = beg; c < end; c += 64) {
                int cnt = min(64, end - c);
                int my_s = 0; float p = 0.f;
                if (lane < cnt) {
                    my_s = fsrc[c + lane];
                    float t = ss[my_s] + bias;
                    t = t >= 0.f ? t : 0.2f * t;
                    p = __expf(t - m) * inv;
                }
                int ngroups = (cnt + 3) >> 2;
                for (int g = 0; g < ngroups; g++) {
                    int ei = g * 4 + q4;
                    int s1 = __shfl(my_s, ei); float w1 = __shfl(p, ei);
                    uint4 x1 = Hb16[(size_t)s1 * 16 + fi];
                    f[0] += w1 * bflo(x1.x); f[1] += w1 * bfhi(x1.x);
                    f[2] += w1 * bflo(x1.y); f[3] += w1 * bfhi(x1.y);
                    f[4] += w1 * bflo(x1.z); f[5] += w1 * bfhi(x1.z);
                    f[6] += w1 * bflo(x1.w); f[7] += w1 * bfhi(x1.w);
                }
            }
        }
        // cross-quarter reduction: quarters hold partial sums of the same features
        #pragma unroll
        for (int k = 0; k < 8; k++) {
            f[k] += __shfl_xor(f[k], 16);
            f[k] += __shfl_xor(f[k], 32);
        }
        if (q4 == 0) {
            uint d0 = (uint)(ushort)f2bf(f[0]) | ((uint)(ushort)f2bf(f[1]) << 16);
            uint d1 = (uint)(ushort)f2bf(f[2]) | ((uint)(ushort)f2bf(f[3]) << 16);
            uint d2 = (uint)(ushort)f2bf(f[4]) | ((uint)(ushort)f2bf(f[5]) << 16);
            uint d3 = (uint)(ushort)f2bf(f[6]) | ((uint)(ushort)f2bf(f[7]) << 16);
            *(uint4*)&tile[(wv * 4 + it) * 72 + fi * 4] = make_uint4(d0, d1, d2, d3);
        }
    }
    __syncthreads();

    // ---- linear2 on the 16x128 LDS tile: wave wv computes cols wv*16..wv*16+15 ----
    int m_l = lane & 15, q = lane >> 4;
    const short8* Bp = (const short8*)W2f;
    float4v acc = {};
    #pragma unroll
    for (int kc = 0; kc < 4; kc++) {
        // A-frag: row m_l, bf16 elems kc*32+q*8.. +7  ->  dwords kc*16+q*4.. +3
        short8 afr = *(const short8*)&tile[m_l * 72 + kc * 16 + q * 4];
        short8 b = Bp[(kc * 4 + wv) * 64 + lane];
        acc = __builtin_amdgcn_mfma_f32_16x16x32_bf16(afr, b, acc, 0, 0, 0);
    }
    int col = wv * 16 + m_l;
    float bias2 = b2[col];
    float aw0 = a2w[col], aw1 = a2w[OUTF + col];
    float vs_r[4], vt_r[4];
    #pragma unroll
    for (int r = 0; r < 4; r++) {
        int row = q * 4 + r;
        float v = acc[r] + bias2;
        vs_r[r] = v * aw0; vt_r[r] = v * aw1;
        Ob[(size_t)(blockIdx.x * 16 + row) * OUTF + col] = (ushort)f2bf(v);
    }
    #pragma unroll
    for (int r = 0; r < 4; r++) {
        #pragma unroll
        for (int o = 1; o < 16; o <<= 1) {
            vs_r[r] += __shfl_xor(vs_r[r], o);
            vt_r[r] += __shfl_xor(vt_r[r], o);
        }
    }
    if (m_l == 0) {
        #pragma unroll
        for (int r = 0; r < 4; r++) { sAcc[wv][q * 4 + r] = vs_r[r]; sTcc[wv][q * 4 + r] = vt_r[r]; }
    }
    __syncthreads();
    if (threadIdx.x < 16) {
        int row = threadIdx.x;
        s2s[blockIdx.x * 16 + row] = sAcc[0][row] + sAcc[1][row] + sAcc[2][row] + sAcc[3][row];
        s2t[blockIdx.x * 16 + row] = sTcc[0][row] + sTcc[1][row] + sTcc[2][row] + sTcc[3][row];
    }
}

// ---------------- agg2: softmax + gather + log_softmax output ----------------
// Gather vectorized: 8 lanes x 16B (dwordx4) per 128B row => 8 edges per wave-load.
// oct = lane>>3 owns edge j+oct; lane&7 owns features 8*(lane&7)..+7.

__global__ __launch_bounds__(256) void k_agg2f(const uint4* __restrict__ Ob16, const int* __restrict__ nbeg,
                                               const int* __restrict__ ncnt, const int* __restrict__ fsrc,
                                               const float* __restrict__ ss, const float* __restrict__ st_,
                                               const float* __restrict__ ab, float* __restrict__ out) {
    int wid  = (blockIdx.x * 256 + threadIdx.x) >> 6;
    int lane = threadIdx.x & 63;
    if (wid >= NN) return;
    int oct = lane >> 3, fi = lane & 7;
    int beg = __builtin_amdgcn_readfirstlane(nbeg[wid]);
    int deg = __builtin_amdgcn_readfirstlane(ncnt[wid]);
    int end = beg + deg;
    float bias = ab[0] + st_[wid];
    float f[8];
    #pragma unroll
    for (int k = 0; k < 8; k++) f[k] = 0.f;

    if (deg > 0 && deg <= 64) {
        int my_s = 0; float a = -INFINITY;
        if (lane < deg) {
            my_s = fsrc[beg + lane];
            float t = ss[my_s] + bias;
            a = t >= 0.f ? t : 0.2f * t;
        }
        float m = a;
        #pragma unroll
        for (int o = 32; o > 0; o >>= 1) m = fmaxf(m, __shfl_xor(m, o));
        float e = (lane < deg) ? __expf(a - m) : 0.f;
        float sum = e;
        #pragma unroll
        for (int o = 32; o > 0; o >>= 1) sum += __shfl_xor(sum, o);
        float p = e * (1.f / (sum + 1e-16f));
        int ngroups = (deg + 7) >> 3;        // edges beyond deg carry p=0
        int s0 = __shfl(my_s, oct); float w0 = __shfl(p, oct);
        uint4 x0 = Ob16[(size_t)s0 * 8 + fi];
        for (int g = 1; g < ngroups; g++) {
            int ei = g * 8 + oct;
            int s1 = __shfl(my_s, ei); float w1 = __shfl(p, ei);
            uint4 x1 = Ob16[(size_t)s1 * 8 + fi];
            f[0] += w0 * bflo(x0.x); f[1] += w0 * bfhi(x0.x);
            f[2] += w0 * bflo(x0.y); f[3] += w0 * bfhi(x0.y);
            f[4] += w0 * bflo(x0.z); f[5] += w0 * bfhi(x0.z);
            f[6] += w0 * bflo(x0.w); f[7] += w0 * bfhi(x0.w);
            x0 = x1; w0 = w1;
        }
        f[0] += w0 * bflo(x0.x); f[1] += w0 * bfhi(x0.x);
        f[2] += w0 * bflo(x0.y); f[3] += w0 * bfhi(x0.y);
        f[4] += w0 * bflo(x0.z); f[5] += w0 * bfhi(x0.z);
        f[6] += w0 * bflo(x0.w); f[7] += w0 * bfhi(x0.w);
    } else if (deg > 64) {
        float m = -INFINITY;
        for (int i = beg + lane; i < end; i += 64) {
            float t = ss[fsrc[i]] + bias;
            t = t >= 0.f ? t : 0.2f * t;
            m = fmaxf(m, t);
        }
        #pragma unroll
        for (int o = 32; o > 0; o >>= 1) m = fmaxf(m, __shfl_xor(m, o));
        float sum = 0.f;
        for (int i = beg + lane; i < end; i += 64) {
            float t = ss[fsrc[i]] + bias;
            t = t >= 0.f ? t : 0.2f * t;
            sum += __expf(t - m);
        }
        #pragma unroll
        for (int o = 32; o > 0; o >>= 1) sum += __shfl_xor(sum, o);
        float inv = 1.f / (sum + 1e-16f);
        for (int c = beg; c < end; c += 64) {
            int cnt = min(64, end - c);
            int my_s = 0; float p = 0.f;
            if (lane < cnt) {
                my_s = fsrc[c + lane];
                float t = ss[my_s] + bias;
                t = t >= 0.f ? t : 0.2f * t;
                p = __expf(t - m) * inv;
            }
            int ngroups = (cnt + 7) >> 3;
            for (int g = 0; g < ngroups; g++) {
                int ei = g * 8 + oct;
                int s1 = __shfl(my_s, ei); float w1 = __shfl(p, ei);
                uint4 x1 = Ob16[(size_t)s1 * 8 + fi];
                f[0] += w1 * bflo(x1.x); f[1] += w1 * bfhi(x1.x);
                f[2] += w1 * bflo(x1.y); f[3] += w1 * bfhi(x1.y);
                f[4] += w1 * bflo(x1.z); f[5] += w1 * bfhi(x1.z);
                f[6] += w1 * bflo(x1.w); f[7] += w1 * bfhi(x1.w);
            }
        }
    }
    // cross-oct reduction: octs hold partials of the same features
    #pragma unroll
    for (int k = 0; k < 8; k++) {
        f[k] += __shfl_xor(f[k], 8);
        f[k] += __shfl_xor(f[k], 16);
        f[k] += __shfl_xor(f[k], 32);
    }
    // log_softmax over 64 features: lane fi owns features 8*fi..8*fi+7 (replicated across octs)
    float mx = f[0];
    #pragma unroll
    for (int k = 1; k < 8; k++) mx = fmaxf(mx, f[k]);
    #pragma unroll
    for (int o = 1; o < 8; o <<= 1) mx = fmaxf(mx, __shfl_xor(mx, o));
    float es = 0.f;
    #pragma unroll
    for (int k = 0; k < 8; k++) es += __expf(f[k] - mx);
    #pragma unroll
    for (int o = 1; o < 8; o <<= 1) es += __shfl_xor(es, o);
    float lg = __logf(es) + mx;
    if (oct == 0) {
        float4 r0, r1;
        r0.x = f[0] - lg; r0.y = f[1] - lg; r0.z = f[2] - lg; r0.w = f[3] - lg;
        r1.x = f[4] - lg; r1.y = f[5] - lg; r1.z = f[6] - lg; r1.w = f[7] - lg;
        float4* po = (float4*)(out + (size_t)wid * 64 + fi * 8);
        po[0] = r0; po[1] = r1;
    }
}

// ---------------- launcher ----------------

extern "C" void kernel_launch(void* const* d_in, const int* in_sizes, int n_in,
                              void* d_out, int out_size, void* d_ws, size_t ws_size,
                              hipStream_t stream) {
    const float* X   = (const float*)d_in[0];
    const int*   ei  = (const int*)d_in[1];
    const float* W1  = (const float*)d_in[2];
    const float* b1  = (const float*)d_in[3];
    const float* a1w = (const float*)d_in[4];
    const float* a1b = (const float*)d_in[5];
    const float* W2  = (const float*)d_in[6];
    const float* b2  = (const float*)d_in[7];
    const float* a2w = (const float*)d_in[8];
    const float* a2b = (const float*)d_in[9];
    const int* src = ei;           // edge_index[0]
    const int* tgt = ei + NE;      // edge_index[1]

    char* p = (char*)d_ws;
    size_t off = 0;
    auto alloc = [&](size_t bytes) -> char* {
        char* r = p + off;
        off = (off + bytes + 255) & ~(size_t)255;
        return r;
    };
    ushort* Hb    = (ushort*)alloc((size_t)NN * HIDF * 2);
    ushort* Ob    = (ushort*)alloc((size_t)NN * OUTF * 2);
    short* W1f    = (short*)alloc((size_t)INF_ * HIDF * 2);
    short* W2f    = (short*)alloc((size_t)HIDF * OUTF * 2);
    float* s1s    = (float*)alloc((size_t)NN * 4);
    float* s1t    = (float*)alloc((size_t)NN * 4);
    float* s2s    = (float*)alloc((size_t)NN * 4);
    float* s2t    = (float*)alloc((size_t)NN * 4);
    int*   bcur   = (int*)alloc((size_t)NBUCK * 4);
    uint*  pairs  = (uint*)alloc((size_t)NBUCK * CAP * 4);
    int*   fsrc   = (int*)alloc((size_t)NBUCK * CAP * 4);
    int*   nbeg   = (int*)alloc((size_t)NN * 4);
    int*   ncnt   = (int*)alloc((size_t)NN * 4);

    k_prep   <<<NPREP + 1, 256, 0, stream>>>(W1, W2, W1f, W2f, bcur);
    k_f1     <<<NPART1 + NLIN1B, 256, 0, stream>>>(src, tgt, bcur, pairs,
                                                   X, W1f, b1, Hb, a1w, s1s, s1t);
    k_part2  <<<NBUCK, 512, 0, stream>>>(bcur, pairs, fsrc, nbeg, ncnt);
    k_agg1l2 <<<NAGG1, 256, 0, stream>>>((const uint4*)Hb, nbeg, ncnt, fsrc, s1s, s1t, a1b,
                                         W2f, b2, a2w, Ob, s2s, s2t);
    k_agg2f  <<<NN / 4, 256, 0, stream>>>((const uint4*)Ob, nbeg, ncnt, fsrc, s2s, s2t, a2b, (float*)d_out);
}

// Round 11
// 207.503 us; speedup vs baseline: 1.0123x; 1.0010x over previous
//
#include <hip/hip_runtime.h>

#define NN    50000
#define NE    800000
#define INF_  256
#define HIDF  128
#define OUTF  64
#define NBUCK 196        // ceil(50000/256) coarse buckets, 256 nodes each
#define CAP   5120       // per-bucket region capacity
#define CHUNK 2048       // edges per part1 block (2048 proven best: scatter-write granularity)
#define NPART1 ((NE + CHUNK - 1) / CHUNK)   // 391
#define NLIN1B ((NN + 127) / 128)           // 391  (fused linear1 grid, 32 rows/wave)
#define NAGG1  (NN / 16)                    // 3125 (fused agg1+linear2 grid, 16 nodes/block)
#define NPREP  160                          // 40960 / 256

typedef unsigned int uint;
typedef unsigned short ushort;
typedef __attribute__((ext_vector_type(8))) short short8;
typedef __attribute__((ext_vector_type(4))) float float4v;

__device__ __forceinline__ short f2bf(float f) {
    union { float f; unsigned u; } v; v.f = f;
    unsigned r = v.u + 0x7fffu + ((v.u >> 16) & 1u);   // round-to-nearest-even
    return (short)(r >> 16);
}
__device__ __forceinline__ float bflo(uint u) {
    union { uint u; float f; } v; v.u = u << 16; return v.f;
}
__device__ __forceinline__ float bfhi(uint u) {
    union { uint u; float f; } v; v.u = u & 0xffff0000u; return v.f;
}

// 256-thread block exclusive scan (ws = 4-int shared scratch). All 256 call.
__device__ __forceinline__ int excl_scan256(int v, int* ws) {
    int lane = threadIdx.x & 63, wv = threadIdx.x >> 6;
    int x = v;
    #pragma unroll
    for (int o = 1; o < 64; o <<= 1) {
        int y = __shfl_up(x, o);
        if (lane >= o) x += y;
    }
    if (lane == 63) ws[wv] = x;
    __syncthreads();
    int add = 0;
    #pragma unroll
    for (int w = 0; w < 4; w++) add += (w < wv) ? ws[w] : 0;
    return x + add - v;
}

// 512-thread block exclusive scan (ws = 8-int shared scratch). All 512 call.
__device__ __forceinline__ int excl_scan512(int v, int* ws) {
    int lane = threadIdx.x & 63, wv = threadIdx.x >> 6;   // wv in 0..7
    int x = v;
    #pragma unroll
    for (int o = 1; o < 64; o <<= 1) {
        int y = __shfl_up(x, o);
        if (lane >= o) x += y;
    }
    if (lane == 63) ws[wv] = x;
    __syncthreads();
    int add = 0;
    #pragma unroll
    for (int w = 0; w < 8; w++) add += (w < wv) ? ws[w] : 0;
    return x + add - v;
}

// ---------------- prep: weight transpose to MFMA B-fragment order + zero bcur ----------------
__global__ __launch_bounds__(256) void k_prep(const float* __restrict__ W1, const float* __restrict__ W2,
                                              short* __restrict__ W1f, short* __restrict__ W2f,
                                              int* __restrict__ bcur) {
    if (blockIdx.x == NPREP) {
        if (threadIdx.x < NBUCK) bcur[threadIdx.x] = 0;
        return;
    }
    int i = blockIdx.x * 256 + threadIdx.x;
    if (i < INF_ * HIDF) {
        int kk = i & 7, t = i >> 3;
        int m_l = t & 15, q = (t >> 4) & 3, s = t >> 6;
        int nb = s & 7, kc = s >> 3;
        int k = kc * 32 + q * 8 + kk, n = nb * 16 + m_l;
        W1f[i] = f2bf(W1[k * HIDF + n]);
    } else if (i < INF_ * HIDF + HIDF * OUTF) {
        int i2 = i - INF_ * HIDF;
        int kk = i2 & 7, t = i2 >> 3;
        int m_l = t & 15, q = (t >> 4) & 3, s = t >> 6;
        int nb = s & 3, kc = s >> 2;
        int k = kc * 32 + q * 8 + kk, n = nb * 16 + m_l;
        W2f[i2] = f2bf(W2[k * OUTF + n]);
    }
}

// ---------------- fused: part1 (coarse bucket sort, PACKED pairs) + linear1 (+s1 epilogue) ----------------
// tgt,src < 50000 < 2^16: pack (tgt<<16)|src into one uint -> halves scatter bytes.

__global__ __launch_bounds__(256, 2) void k_f1(const int* __restrict__ src, const int* __restrict__ tgt,
                                               int* __restrict__ bcur, uint* __restrict__ pairs,
                                               const float* __restrict__ X, const short* __restrict__ W1f,
                                               const float* __restrict__ b1, ushort* __restrict__ Hb,
                                               const float* __restrict__ a1w, float* __restrict__ s1s,
                                               float* __restrict__ s1t) {
    if (blockIdx.x < NPART1) {
        // ================= part1 =================
        __shared__ int hist[NBUCK], lofs[NBUCK], cur[NBUCK], gstart[NBUCK];
        __shared__ int ws[4];
        __shared__ uint lpack[CHUNK];
        int tid = threadIdx.x;
        for (int i = tid; i < NBUCK; i += 256) hist[i] = 0;
        __syncthreads();

        int base = blockIdx.x * CHUNK;
        int cnt = NE - base; if (cnt > CHUNK) cnt = CHUNK;

        int t_[8], s_[8];
        #pragma unroll
        for (int k = 0; k < 8; k++) {
            int idx = k * 256 + tid;
            if (idx < cnt) {
                int j = base + idx;
                t_[k] = tgt[j]; s_[k] = src[j];
                atomicAdd(&hist[t_[k] >> 8], 1);
            } else t_[k] = -1;
        }
        __syncthreads();

        int v = (tid < NBUCK) ? hist[tid] : 0;
        int excl = excl_scan256(v, ws);
        if (tid < NBUCK) {
            lofs[tid] = excl;
            cur[tid] = excl;
            gstart[tid] = atomicAdd(&bcur[tid], v);
        }
        __syncthreads();

        #pragma unroll
        for (int k = 0; k < 8; k++) {
            if (t_[k] >= 0) {
                int b = t_[k] >> 8;
                int pos = atomicAdd(&cur[b], 1);
                lpack[pos] = ((uint)t_[k] << 16) | (uint)s_[k];
            }
        }
        __syncthreads();

        for (int j = tid; j < cnt; j += 256) {
            uint pk = lpack[j];
            int b = pk >> 24;                 // tgt>>8
            int dst = gstart[b] + (j - lofs[b]);
            pairs[(size_t)b * CAP + dst] = pk;
        }
        return;
    }
    // ================= linear1 + s1 : 32 rows per wave (2 MFMA A-tiles) =================
    int bid = blockIdx.x - NPART1;
    int w = threadIdx.x >> 6;
    int l = threadIdx.x & 63;
    int m_l = l & 15, q = l >> 4;
    int row0 = bid * 128 + w * 32;
    int rA0 = row0 + m_l;
    int rA1 = row0 + 16 + m_l;
    int rc0 = rA0 < NN ? rA0 : NN - 1;
    int rc1 = rA1 < NN ? rA1 : NN - 1;
    const float* pa0 = X + (size_t)rc0 * INF_ + q * 8;
    const float* pa1 = X + (size_t)rc1 * INF_ + q * 8;
    const short8* Bp = (const short8*)W1f;

    float4 xu[2][4];
    short8 bb[2][8];
    xu[0][0] = *(const float4*)(pa0);
    xu[0][1] = *(const float4*)(pa0 + 4);
    xu[0][2] = *(const float4*)(pa1);
    xu[0][3] = *(const float4*)(pa1 + 4);
    #pragma unroll
    for (int n = 0; n < 8; n++) bb[0][n] = Bp[n * 64 + l];

    float4v acc0[8] = {}, acc1[8] = {};
    #pragma unroll
    for (int kc = 0; kc < 8; kc++) {
        const int cur_ = kc & 1, nxt = cur_ ^ 1;
        if (kc < 7) {
            xu[nxt][0] = *(const float4*)(pa0 + (kc + 1) * 32);
            xu[nxt][1] = *(const float4*)(pa0 + (kc + 1) * 32 + 4);
            xu[nxt][2] = *(const float4*)(pa1 + (kc + 1) * 32);
            xu[nxt][3] = *(const float4*)(pa1 + (kc + 1) * 32 + 4);
            #pragma unroll
            for (int n = 0; n < 8; n++) bb[nxt][n] = Bp[((kc + 1) * 8 + n) * 64 + l];
        }
        float4 u0 = xu[cur_][0], u1 = xu[cur_][1], v0 = xu[cur_][2], v1 = xu[cur_][3];
        short8 af0, af1;
        af0[0] = f2bf(u0.x); af0[1] = f2bf(u0.y); af0[2] = f2bf(u0.z); af0[3] = f2bf(u0.w);
        af0[4] = f2bf(u1.x); af0[5] = f2bf(u1.y); af0[6] = f2bf(u1.z); af0[7] = f2bf(u1.w);
        af1[0] = f2bf(v0.x); af1[1] = f2bf(v0.y); af1[2] = f2bf(v0.z); af1[3] = f2bf(v0.w);
        af1[4] = f2bf(v1.x); af1[5] = f2bf(v1.y); af1[6] = f2bf(v1.z); af1[7] = f2bf(v1.w);
        #pragma unroll
        for (int n = 0; n < 8; n++) {
            acc0[n] = __builtin_amdgcn_mfma_f32_16x16x32_bf16(af0, bb[cur_][n], acc0[n], 0, 0, 0);
            acc1[n] = __builtin_amdgcn_mfma_f32_16x16x32_bf16(af1, bb[cur_][n], acc1[n], 0, 0, 0);
        }
    }

    float vs_r[8], vt_r[8];
    #pragma unroll
    for (int r = 0; r < 8; r++) { vs_r[r] = 0.f; vt_r[r] = 0.f; }
    #pragma unroll
    for (int n = 0; n < 8; n++) {
        int col = n * 16 + m_l;
        float bias = b1[col];
        float aw0 = a1w[col], aw1 = a1w[HIDF + col];
        #pragma unroll
        for (int r = 0; r < 4; r++) {
            int row = row0 + q * 4 + r;
            float v = acc0[n][r] + bias;
            v = v > 0.f ? v : expm1f(v);   // elu
            vs_r[r] += v * aw0; vt_r[r] += v * aw1;
            if (row < NN) Hb[(size_t)row * HIDF + col] = (ushort)f2bf(v);

            int row1 = row0 + 16 + q * 4 + r;
            float v1 = acc1[n][r] + bias;
            v1 = v1 > 0.f ? v1 : expm1f(v1);   // elu
            vs_r[4 + r] += v1 * aw0; vt_r[4 + r] += v1 * aw1;
            if (row1 < NN) Hb[(size_t)row1 * HIDF + col] = (ushort)f2bf(v1);
        }
    }
    #pragma unroll
    for (int r = 0; r < 8; r++) {
        #pragma unroll
        for (int o = 1; o < 16; o <<= 1) {
            vs_r[r] += __shfl_xor(vs_r[r], o);
            vt_r[r] += __shfl_xor(vt_r[r], o);
        }
    }
    if (m_l == 0) {
        #pragma unroll
        for (int r = 0; r < 4; r++) {
            int row = row0 + q * 4 + r;
            if (row < NN) { s1s[row] = vs_r[r]; s1t[row] = vt_r[r]; }
            int row1 = row0 + 16 + q * 4 + r;
            if (row1 < NN) { s1s[row1] = vs_r[4 + r]; s1t[row1] = vt_r[4 + r]; }
        }
    }
}

// ---------------- part2: fine sort within bucket (512 threads; packed pairs) ----------------
__global__ __launch_bounds__(512) void k_part2(const int* __restrict__ bcur, const uint* __restrict__ pairs,
                                               int* __restrict__ fsrc, int* __restrict__ nbeg,
                                               int* __restrict__ ncnt) {
    __shared__ int hist[256], cur[256];
    __shared__ int ws[8];
    int tid = threadIdx.x;
    int b = blockIdx.x;
    int cnt = __builtin_amdgcn_readfirstlane(bcur[b]);
    if (tid < 256) hist[tid] = 0;
    __syncthreads();

    const uint* pb = pairs + (size_t)b * CAP;
    for (int j = tid; j < cnt; j += 512) {
        uint e = pb[j];
        atomicAdd(&hist[(e >> 16) & 255], 1);
    }
    __syncthreads();

    int v = (tid < 256) ? hist[tid] : 0;
    int excl = excl_scan512(v, ws);
    if (tid < 256) {
        int node = (b << 8) + tid;
        if (node < NN) { nbeg[node] = b * CAP + excl; ncnt[node] = v; }
        cur[tid] = excl;
    }
    __syncthreads();

    for (int j = tid; j < cnt; j += 512) {
        uint e = pb[j];
        int pos = atomicAdd(&cur[(e >> 16) & 255], 1);
        fsrc[(size_t)b * CAP + pos] = (int)(e & 0xFFFFu);
    }
}

// ---------------- fused agg1 (softmax+gather) + linear2 + s2 epilogue ----------------
// 16 nodes per 256-thread block. Gather vectorized: 16 lanes x 16B (dwordx4) per 256B row,
// so one wave-load fetches 4 edges' rows; quarter q4=lane>>4 owns edge j+q4.
// Node loop unrolled x2: consecutive nodes are independent -> 2 gather chains in flight.
// Then each wave computes one 16-col slice of the 16x128 @ 128x64 MFMA matmul.

__global__ __launch_bounds__(256) void k_agg1l2(const uint4* __restrict__ Hb16, const int* __restrict__ nbeg,
                                                const int* __restrict__ ncnt, const int* __restrict__ fsrc,
                                                const float* __restrict__ ss, const float* __restrict__ st_,
                                                const float* __restrict__ ab,
                                                const short* __restrict__ W2f, const float* __restrict__ b2,
                                                const float* __restrict__ a2w,
                                                ushort* __restrict__ Ob, float* __restrict__ s2s,
                                                float* __restrict__ s2t) {
    __shared__ uint tile[16 * 72];           // 16 rows x 64 dwords, +8 pad (288B stride, 16B-aligned rows)
    __shared__ float sAcc[4][16], sTcc[4][16];
    int wv   = threadIdx.x >> 6;
    int lane = threadIdx.x & 63;
    int q4 = lane >> 4, fi = lane & 15;

    #pragma unroll 2
    for (int it = 0; it < 4; ++it) {
        int wid = blockIdx.x * 16 + wv * 4 + it;   // grid exact: always < NN
        int beg = __builtin_amdgcn_readfirstlane(nbeg[wid]);
        int deg = __builtin_amdgcn_readfirstlane(ncnt[wid]);
        int end = beg + deg;
        float bias = ab[0] + st_[wid];
        float f[8];
        #pragma unroll
        for (int k = 0; k < 8; k++) f[k] = 0.f;

        if (deg > 0 && deg <= 64) {
            int my_s = 0; float a = -INFINITY;
            if (lane < deg) {
                my_s = fsrc[beg + lane];
                float t = ss[my_s] + bias;
                a = t >= 0.f ? t : 0.2f * t;
            }
            float m = a;
            #pragma unroll
            for (int o = 32; o > 0; o >>= 1) m = fmaxf(m, __shfl_xor(m, o));
            float e = (lane < deg) ? __expf(a - m) : 0.f;
            float sum = e;
            #pragma unroll
            for (int o = 32; o > 0; o >>= 1) sum += __shfl_xor(sum, o);
            float p = e * (1.f / (sum + 1e-16f));
            int ngroups = (deg + 3) >> 2;        // wave-uniform; edges beyond deg carry p=0
            int s0 = __shfl(my_s, q4); float w0 = __shfl(p, q4);
            uint4 x0 = Hb16[(size_t)s0 * 16 + fi];
            for (int g = 1; g < ngroups; g++) {
                int ei = g * 4 + q4;
                int s1 = __shfl(my_s, ei); float w1 = __shfl(p, ei);
                uint4 x1 = Hb16[(size_t)s1 * 16 + fi];
                f[0] += w0 * bflo(x0.x); f[1] += w0 * bfhi(x0.x);
                f[2] += w0 * bflo(x0.y); f[3] += w0 * bfhi(x0.y);
                f[4] += w0 * bflo(x0.z); f[5] += w0 * bfhi(x0.z);
                f[6] += w0 * bflo(x0.w); f[7] += w0 * bfhi(x0.w);
                x0 = x1; w0 = w1;
            }
            f[0] += w0 * bflo(x0.x); f[1] += w0 * bfhi(x0.x);
            f[2] += w0 * bflo(x0.y); f[3] += w0 * bfhi(x0.y);
            f[4] += w0 * bflo(x0.z); f[5] += w0 * bfhi(x0.z);
            f[6] += w0 * bflo(x0.w); f[7] += w0 * bfhi(x0.w);
        } else if (deg > 64) {
            float m = -INFINITY;
            for (int i = beg + lane; i < end; i += 64) {
                float t = ss[fsrc[i]] + bias;
                t = t >= 0.f ? t : 0.2f * t;
                m = fmaxf(m, t);
            }
            #pragma unroll
            for (int o = 32; o > 0; o >>= 1) m = fmaxf(m, __shfl_xor(m, o));
            float sum = 0.f;
            for (int i = beg + lane; i < end; i += 64) {
                float t = ss[fsrc[i]] + bias;
                t = t >= 0.f ? t : 0.2f * t;
                sum += __expf(t - m);
            }
            #pragma unroll
            for (int o = 32; o > 0; o >>= 1) sum += __shfl_xor(sum, o);
            float inv = 1.f / (sum + 1e-16f);
            for (int c = beg; c < end; c += 64) {
                int cnt = min(64, end - c);
                int my_s = 0; float p = 0.f;
                if (lane < cnt) {
                    my_s = fsrc[c + lane];
                    float t = ss[my_s] + bias;
                    t = t >= 0.f ? t : 0.2f * t;
                    p = __expf(t - m) * inv;
                }
                int ngroups = (cnt + 3) >> 2;
                for (int g = 0; g < ngroups; g++) {
                    int ei = g * 4 + q4;
                    int s1 = __shfl(my_s, ei); float w1 = __shfl(p, ei);
                    uint4 x1 = Hb16[(size_t)s1 * 16 + fi];
                    f[0] += w1 * bflo(x1.x); f[1] += w1 * bfhi(x1.x);
                    f[2] += w1 * bflo(x1.y); f[3] += w1 * bfhi(x1.y);
                    f[4] += w1 * bflo(x1.z); f[5] += w1 * bfhi(x1.z);
                    f[6] += w1 * bflo(x1.w); f[7] += w1 * bfhi(x1.w);
                }
            }
        }
        // cross-quarter reduction: quarters hold partial sums of the same features
        #pragma unroll
        for (int k = 0; k < 8; k++) {
            f[k] += __shfl_xor(f[k], 16);
            f[k] += __shfl_xor(f[k], 32);
        }
        if (q4 == 0) {
            uint d0 = (uint)(ushort)f2bf(f[0]) | ((uint)(ushort)f2bf(f[1]) << 16);
            uint d1 = (uint)(ushort)f2bf(f[2]) | ((uint)(ushort)f2bf(f[3]) << 16);
            uint d2 = (uint)(ushort)f2bf(f[4]) | ((uint)(ushort)f2bf(f[5]) << 16);
            uint d3 = (uint)(ushort)f2bf(f[6]) | ((uint)(ushort)f2bf(f[7]) << 16);
            *(uint4*)&tile[(wv * 4 + it) * 72 + fi * 4] = make_uint4(d0, d1, d2, d3);
        }
    }
    __syncthreads();

    // ---- linear2 on the 16x128 LDS tile: wave wv computes cols wv*16..wv*16+15 ----
    int m_l = lane & 15, q = lane >> 4;
    const short8* Bp = (const short8*)W2f;
    float4v acc = {};
    #pragma unroll
    for (int kc = 0; kc < 4; kc++) {
        // A-frag: row m_l, bf16 elems kc*32+q*8.. +7  ->  dwords kc*16+q*4.. +3
        short8 afr = *(const short8*)&tile[m_l * 72 + kc * 16 + q * 4];
        short8 b = Bp[(kc * 4 + wv) * 64 + lane];
        acc = __builtin_amdgcn_mfma_f32_16x16x32_bf16(afr, b, acc, 0, 0, 0);
    }
    int col = wv * 16 + m_l;
    float bias2 = b2[col];
    float aw0 = a2w[col], aw1 = a2w[OUTF + col];
    float vs_r[4], vt_r[4];
    #pragma unroll
    for (int r = 0; r < 4; r++) {
        int row = q * 4 + r;
        float v = acc[r] + bias2;
        vs_r[r] = v * aw0; vt_r[r] = v * aw1;
        Ob[(size_t)(blockIdx.x * 16 + row) * OUTF + col] = (ushort)f2bf(v);
    }
    #pragma unroll
    for (int r = 0; r < 4; r++) {
        #pragma unroll
        for (int o = 1; o < 16; o <<= 1) {
            vs_r[r] += __shfl_xor(vs_r[r], o);
            vt_r[r] += __shfl_xor(vt_r[r], o);
        }
    }
    if (m_l == 0) {
        #pragma unroll
        for (int r = 0; r < 4; r++) { sAcc[wv][q * 4 + r] = vs_r[r]; sTcc[wv][q * 4 + r] = vt_r[r]; }
    }
    __syncthreads();
    if (threadIdx.x < 16) {
        int row = threadIdx.x;
        s2s[blockIdx.x * 16 + row] = sAcc[0][row] + sAcc[1][row] + sAcc[2][row] + sAcc[3][row];
        s2t[blockIdx.x * 16 + row] = sTcc[0][row] + sTcc[1][row] + sTcc[2][row] + sTcc[3][row];
    }
}

// ---------------- agg2: softmax + gather + log_softmax output ----------------
// Gather vectorized: 8 lanes x 16B (dwordx4) per 128B row => 8 edges per wave-load.
// oct = lane>>3 owns edge j+oct; lane&7 owns features 8*(lane&7)..+7.

__global__ __launch_bounds__(256) void k_agg2f(const uint4* __restrict__ Ob16, const int* __restrict__ nbeg,
                                               const int* __restrict__ ncnt, const int* __restrict__ fsrc,
                                               const float* __restrict__ ss, const float* __restrict__ st_,
                                               const float* __restrict__ ab, float* __restrict__ out) {
    int wid  = (blockIdx.x * 256 + threadIdx.x) >> 6;
    int lane = threadIdx.x & 63;
    if (wid >= NN) return;
    int oct = lane >> 3, fi = lane & 7;
    int beg = __builtin_amdgcn_readfirstlane(nbeg[wid]);
    int deg = __builtin_amdgcn_readfirstlane(ncnt[wid]);
    int end = beg + deg;
    float bias = ab[0] + st_[wid];
    float f[8];
    #pragma unroll
    for (int k = 0; k < 8; k++) f[k] = 0.f;

    if (deg > 0 && deg <= 64) {
        int my_s = 0; float a = -INFINITY;
        if (lane < deg) {
            my_s = fsrc[beg + lane];
            float t = ss[my_s] + bias;
            a = t >= 0.f ? t : 0.2f * t;
        }
        float m = a;
        #pragma unroll
        for (int o = 32; o > 0; o >>= 1) m = fmaxf(m, __shfl_xor(m, o));
        float e = (lane < deg) ? __expf(a - m) : 0.f;
        float sum = e;
        #pragma unroll
        for (int o = 32; o > 0; o >>= 1) sum += __shfl_xor(sum, o);
        float p = e * (1.f / (sum + 1e-16f));
        int ngroups = (deg + 7) >> 3;        // edges beyond deg carry p=0
        int s0 = __shfl(my_s, oct); float w0 = __shfl(p, oct);
        uint4 x0 = Ob16[(size_t)s0 * 8 + fi];
        for (int g = 1; g < ngroups; g++) {
            int ei = g * 8 + oct;
            int s1 = __shfl(my_s, ei); float w1 = __shfl(p, ei);
            uint4 x1 = Ob16[(size_t)s1 * 8 + fi];
            f[0] += w0 * bflo(x0.x); f[1] += w0 * bfhi(x0.x);
            f[2] += w0 * bflo(x0.y); f[3] += w0 * bfhi(x0.y);
            f[4] += w0 * bflo(x0.z); f[5] += w0 * bfhi(x0.z);
            f[6] += w0 * bflo(x0.w); f[7] += w0 * bfhi(x0.w);
            x0 = x1; w0 = w1;
        }
        f[0] += w0 * bflo(x0.x); f[1] += w0 * bfhi(x0.x);
        f[2] += w0 * bflo(x0.y); f[3] += w0 * bfhi(x0.y);
        f[4] += w0 * bflo(x0.z); f[5] += w0 * bfhi(x0.z);
        f[6] += w0 * bflo(x0.w); f[7] += w0 * bfhi(x0.w);
    } else if (deg > 64) {
        float m = -INFINITY;
        for (int i = beg + lane; i < end; i += 64) {
            float t = ss[fsrc[i]] + bias;
            t = t >= 0.f ? t : 0.2f * t;
            m = fmaxf(m, t);
        }
        #pragma unroll
        for (int o = 32; o > 0; o >>= 1) m = fmaxf(m, __shfl_xor(m, o));
        float sum = 0.f;
        for (int i = beg + lane; i < end; i += 64) {
            float t = ss[fsrc[i]] + bias;
            t = t >= 0.f ? t : 0.2f * t;
            sum += __expf(t - m);
        }
        #pragma unroll
        for (int o = 32; o > 0; o >>= 1) sum += __shfl_xor(sum, o);
        float inv = 1.f / (sum + 1e-16f);
        for (int c = beg; c < end; c += 64) {
            int cnt = min(64, end - c);
            int my_s = 0; float p = 0.f;
            if (lane < cnt) {
                my_s = fsrc[c + lane];
                float t = ss[my_s] + bias;
                t = t >= 0.f ? t : 0.2f * t;
                p = __expf(t - m) * inv;
            }
            int ngroups = (cnt + 7) >> 3;
            for (int g = 0; g < ngroups; g++) {
                int ei = g * 8 + oct;
                int s1 = __shfl(my_s, ei); float w1 = __shfl(p, ei);
                uint4 x1 = Ob16[(size_t)s1 * 8 + fi];
                f[0] += w1 * bflo(x1.x); f[1] += w1 * bfhi(x1.x);
                f[2] += w1 * bflo(x1.y); f[3] += w1 * bfhi(x1.y);
                f[4] += w1 * bflo(x1.z); f[5] += w1 * bfhi(x1.z);
                f[6] += w1 * bflo(x1.w); f[7] += w1 * bfhi(x1.w);
            }
        }
    }
    // cross-oct reduction: octs hold partials of the same features
    #pragma unroll
    for (int k = 0; k < 8; k++) {
        f[k] += __shfl_xor(f[k], 8);
        f[k] += __shfl_xor(f[k], 16);
        f[k] += __shfl_xor(f[k], 32);
    }
    // log_softmax over 64 features: lane fi owns features 8*fi..8*fi+7 (replicated across octs)
    float mx = f[0];
    #pragma unroll
    for (int k = 1; k < 8; k++) mx = fmaxf(mx, f[k]);
    #pragma unroll
    for (int o = 1; o < 8; o <<= 1) mx = fmaxf(mx, __shfl_xor(mx, o));
    float es = 0.f;
    #pragma unroll
    for (int k = 0; k < 8; k++) es += __expf(f[k] - mx);
    #pragma unroll
    for (int o = 1; o < 8; o <<= 1) es += __shfl_xor(es, o);
    float lg = __logf(es) + mx;
    if (oct == 0) {
        float4 r0, r1;
        r0.x = f[0] - lg; r0.y = f[1] - lg; r0.z = f[2] - lg; r0.w = f[3] - lg;
        r1.x = f[4] - lg; r1.y = f[5] - lg; r1.z = f[6] - lg; r1.w = f[7] - lg;
        float4* po = (float4*)(out + (size_t)wid * 64 + fi * 8);
        po[0] = r0; po[1] = r1;
    }
}

// ---------------- launcher ----------------

extern "C" void kernel_launch(void* const* d_in, const int* in_sizes, int n_in,
                              void* d_out, int out_size, void* d_ws, size_t ws_size,
                              hipStream_t stream) {
    const float* X   = (const float*)d_in[0];
    const int*   ei  = (const int*)d_in[1];
    const float* W1  = (const float*)d_in[2];
    const float* b1  = (const float*)d_in[3];
    const float* a1w = (const float*)d_in[4];
    const float* a1b = (const float*)d_in[5];
    const float* W2  = (const float*)d_in[6];
    const float* b2  = (const float*)d_in[7];
    const float* a2w = (const float*)d_in[8];
    const float* a2b = (const float*)d_in[9];
    const int* src = ei;           // edge_index[0]
    const int* tgt = ei + NE;      // edge_index[1]

    char* p = (char*)d_ws;
    size_t off = 0;
    auto alloc = [&](size_t bytes) -> char* {
        char* r = p + off;
        off = (off + bytes + 255) & ~(size_t)255;
        return r;
    };
    ushort* Hb    = (ushort*)alloc((size_t)NN * HIDF * 2);
    ushort* Ob    = (ushort*)alloc((size_t)NN * OUTF * 2);
    short* W1f    = (short*)alloc((size_t)INF_ * HIDF * 2);
    short* W2f    = (short*)alloc((size_t)HIDF * OUTF * 2);
    float* s1s    = (float*)alloc((size_t)NN * 4);
    float* s1t    = (float*)alloc((size_t)NN * 4);
    float* s2s    = (float*)alloc((size_t)NN * 4);
    float* s2t    = (float*)alloc((size_t)NN * 4);
    int*   bcur   = (int*)alloc((size_t)NBUCK * 4);
    uint*  pairs  = (uint*)alloc((size_t)NBUCK * CAP * 4);
    int*   fsrc   = (int*)alloc((size_t)NBUCK * CAP * 4);
    int*   nbeg   = (int*)alloc((size_t)NN * 4);
    int*   ncnt   = (int*)alloc((size_t)NN * 4);

    k_prep   <<<NPREP + 1, 256, 0, stream>>>(W1, W2, W1f, W2f, bcur);
    k_f1     <<<NPART1 + NLIN1B, 256, 0, stream>>>(src, tgt, bcur, pairs,
                                                   X, W1f, b1, Hb, a1w, s1s, s1t);
    k_part2  <<<NBUCK, 512, 0, stream>>>(bcur, pairs, fsrc, nbeg, ncnt);
    k_agg1l2 <<<NAGG1, 256, 0, stream>>>((const uint4*)Hb, nbeg, ncnt, fsrc, s1s, s1t, a1b,
                                         W2f, b2, a2w, Ob, s2s, s2t);
    k_agg2f  <<<NN / 4, 256, 0, stream>>>((const uint4*)Ob, nbeg, ncnt, fsrc, s2s, s2t, a2b, (float*)d_out);
}